// Round 1
// 1024.102 us; speedup vs baseline: 1.0325x; 1.0325x over previous
//
#include <hip/hip_runtime.h>

typedef unsigned short u16;
typedef unsigned int u32;

#define T_ 2048
#define B_ 16
#define D_ 1024
constexpr int MM = T_ * B_;     // 32768 GEMM rows
constexpr int KK = D_;          // 1024
constexpr int NN = 2 * D_;      // 2048 (alpha cols | v cols)
constexpr int BD = B_ * D_;     // 16384
constexpr int BM = 128, BN = 128, BK = 32;

typedef __bf16 bf16x8 __attribute__((ext_vector_type(8)));
typedef float f32x4 __attribute__((ext_vector_type(4)));

typedef __attribute__((address_space(3))) u32 lds_u32_t;
typedef __attribute__((address_space(1))) u32 gbl_u32_t;

__device__ __forceinline__ void gld16(void* lds, const void* g) {
    // async global->LDS, 16B per lane, dest = wave-uniform base + lane*16
    __builtin_amdgcn_global_load_lds((const gbl_u32_t*)g, (lds_u32_t*)lds, 16, 0, 0);
}

__device__ __forceinline__ float fast_sig(float x) {
    return __builtin_amdgcn_rcpf(1.0f + __expf(-x));
}

__device__ __forceinline__ float fast_exp2(float x) {
#if __has_builtin(__builtin_amdgcn_exp2f)
    return __builtin_amdgcn_exp2f(x);
#else
    return exp2f(x);
#endif
}

// ---------------- split fp32 -> bf16 hi/lo (truncation; lo corrects hi) ----
__device__ inline void split1(float f, u16& h, u16& l) {
    u32 u = __float_as_uint(f);
    h = (u16)(u >> 16);
    float fh = __uint_as_float(u & 0xffff0000u);
    float r = f - fh;                   // exact (low mantissa bits)
    l = (u16)(__float_as_uint(r) >> 16);
}

__global__ __launch_bounds__(256) void split_kernel(
    const float* __restrict__ src, u16* __restrict__ hi, u16* __restrict__ lo, int n4)
{
    int i = blockIdx.x * 256 + threadIdx.x;
    if (i >= n4) return;
    float4 v = ((const float4*)src)[i];
    u16 h0, h1, h2, h3, l0, l1, l2, l3;
    split1(v.x, h0, l0); split1(v.y, h1, l1);
    split1(v.z, h2, l2); split1(v.w, h3, l3);
    ushort4 hv; hv.x = h0; hv.y = h1; hv.z = h2; hv.w = h3;
    ushort4 lv; lv.x = l0; lv.y = l1; lv.z = l2; lv.w = l3;
    ((ushort4*)hi)[i] = hv;
    ((ushort4*)lo)[i] = lv;
}

// ---------------- fused dual GEMM: [32768,1024] x [2048,1024]^T ------------
// n<1024 -> sigmoid(.+b_alpha) = alpha  -> h region slot t+1
// n>=1024 -> tanh(.+b_v)       = v_raw  -> out region
__global__ __launch_bounds__(256) void gemm_dual(
    const u16* __restrict__ xhi, const u16* __restrict__ xlo,
    const u16* __restrict__ whi, const u16* __restrict__ wlo,
    const float* __restrict__ ba, const float* __restrict__ bv,
    float* __restrict__ out_ptr, float* __restrict__ h_ptr)
{
    __shared__ u16 Ah[BM][BK];   // 8 KB each, rows 64B, unpadded (gld16 needs this)
    __shared__ u16 Al[BM][BK];
    __shared__ u16 Bh[BN][BK];
    __shared__ u16 Bl[BN][BK];

    const int tid  = threadIdx.x;
    const int m0   = blockIdx.y * BM;
    const int n0   = blockIdx.x * BN;
    const int wave = tid >> 6, lane = tid & 63;
    const int wm = (wave & 1) << 6;     // wave's 64-row region for MFMA
    const int wn = (wave >> 1) << 6;    // wave's 64-col region
    const int fm = lane & 15, quad = lane >> 4;
    const int wb = wave << 5;           // staging: wave covers 32 rows (2 calls x 16)
    const int rl = lane >> 2;           // staging row within 16-row group
    const int cl = (lane & 3) << 3;     // staging col (elements), 16B per lane

    f32x4 acc[4][4] = {};

    for (int k0 = 0; k0 < KK; k0 += BK) {
        size_t ga = (size_t)(m0 + wb + rl) * KK + k0 + cl;
        size_t gb = (size_t)(n0 + wb + rl) * KK + k0 + cl;
        gld16(&Ah[wb][0],      xhi + ga);
        gld16(&Ah[wb + 16][0], xhi + ga + (size_t)16 * KK);
        gld16(&Al[wb][0],      xlo + ga);
        gld16(&Al[wb + 16][0], xlo + ga + (size_t)16 * KK);
        gld16(&Bh[wb][0],      whi + gb);
        gld16(&Bh[wb + 16][0], whi + gb + (size_t)16 * KK);
        gld16(&Bl[wb][0],      wlo + gb);
        gld16(&Bl[wb + 16][0], wlo + gb + (size_t)16 * KK);
        __syncthreads();   // drains vmcnt -> LDS data visible

        bf16x8 ah[4], al[4], bh[4], bl[4];
        #pragma unroll
        for (int i = 0; i < 4; ++i) {
            ah[i] = *(const bf16x8*)&Ah[wm + i * 16 + fm][quad * 8];
            al[i] = *(const bf16x8*)&Al[wm + i * 16 + fm][quad * 8];
            bh[i] = *(const bf16x8*)&Bh[wn + i * 16 + fm][quad * 8];
            bl[i] = *(const bf16x8*)&Bl[wn + i * 16 + fm][quad * 8];
        }
        #pragma unroll
        for (int mi = 0; mi < 4; ++mi) {
            #pragma unroll
            for (int ni = 0; ni < 4; ++ni) {
                acc[mi][ni] = __builtin_amdgcn_mfma_f32_16x16x32_bf16(ah[mi], bh[ni], acc[mi][ni], 0, 0, 0);
                acc[mi][ni] = __builtin_amdgcn_mfma_f32_16x16x32_bf16(ah[mi], bl[ni], acc[mi][ni], 0, 0, 0);
                acc[mi][ni] = __builtin_amdgcn_mfma_f32_16x16x32_bf16(al[mi], bh[ni], acc[mi][ni], 0, 0, 0);
            }
        }
        __syncthreads();
    }

    const bool is_alpha = (n0 < D_);
    #pragma unroll
    for (int mi = 0; mi < 4; ++mi) {
        #pragma unroll
        for (int ni = 0; ni < 4; ++ni) {
            const int nglob = n0 + wn + ni * 16 + fm;   // C/D col = lane&15
            #pragma unroll
            for (int r = 0; r < 4; ++r) {
                const int mglob = m0 + wm + mi * 16 + quad * 4 + r;  // row=(lane>>4)*4+reg
                float z = acc[mi][ni][r];
                if (is_alpha) {
                    z += ba[nglob];
                    float s = 1.0f / (1.0f + __expf(-z));
                    h_ptr[(size_t)BD + (size_t)mglob * D_ + nglob] = s;  // alpha[t] at h slot t+1
                } else {
                    int nn = nglob - D_;
                    z += bv[nn];
                    out_ptr[(size_t)mglob * D_ + nn] = tanhf(z);         // v_raw[t] at out slot t
                }
            }
        }
    }
}

// ---------------- sequential self-gating scan ------------------------------
// In-place layout: alpha[t] lives at h slot t+1, v_raw[t] at out slot t.
// The four streams are passed as DISTINCT __restrict__ params even though
// alpha_p==hout_p and vraw_p==out_p: dynamically there is never an in-flight
// load that aliases a store (the load of slot t is consumed -- vmcnt-waited
// by its VALU use -- before the store of slot t issues, since the stored h
// data-depends on the loaded alpha; all other pending loads target slots
// strictly ahead of every store). Declaring no-alias lets the compiler drop
// the conservative per-store s_waitcnt that was serializing the prefetch
// pipeline to memory-latency speed (~490 cyc/iter).
// Chunk-level double buffering: all 32 loads of chunk n+1 issue back-to-back
// before chunk n's compute, so even a surviving wait amortizes over 16 steps.
#define SCAN_BODY(A_, V_) do {                                        \
    float a_  = (A_);                                                 \
    float vr_ = (V_);                                                 \
    float e_  = fast_exp2(__builtin_fmaf(ndg, h, nbg));               \
    float g_  = __builtin_amdgcn_rcpf(1.0f + e_);                     \
    float v_  = vr_ * g_;                                             \
    h = __builtin_fmaf(a_, h - v_, v_);                               \
    float e2_ = fast_exp2(h * -1.44269504088896f);                    \
    float sg_ = __builtin_amdgcn_rcpf(1.0f + e2_);                    \
    __builtin_nontemporal_store(h * h * sg_, po + (size_t)t * BD);    \
    __builtin_nontemporal_store(h, ph + (size_t)t * BD);              \
    ++t;                                                              \
} while (0)

__global__ __launch_bounds__(64) void scan_kernel(
    const float* __restrict__ alpha_p,   // = h_ptr + BD   (alpha[t] at t*BD)
    const float* __restrict__ vraw_p,    // = out_ptr      (v_raw[t] at t*BD)
    float* __restrict__ out_p,           // = out_ptr      (out[t]   at t*BD)
    float* __restrict__ hout_p,          // = h_ptr + BD   (h[t+1]   at t*BD)
    float* __restrict__ h0_dst,          // = h_ptr        (h[0])
    const float* __restrict__ h0,
    const float* __restrict__ d_g, const float* __restrict__ b_g)
{
    const int i = blockIdx.x * 64 + threadIdx.x;   // 0..BD-1
    const int d = i & (D_ - 1);
    constexpr float L2E = 1.44269504088896f;
    const float ndg = -d_g[d] * L2E;               // fold sigmoid arg into exp2 form
    const float nbg = -b_g[d] * L2E;
    float h = h0[i];
    h0_dst[i] = h;                                 // h[0]

    const float* pa = alpha_p + i;
    const float* pv = vraw_p + i;
    float* po = out_p + i;
    float* ph = hout_p + i;

    constexpr int PF = 16;
    constexpr int NC = T_ / PF;                    // 128 chunks
    float a0[PF], v0[PF], a1[PF], v1[PF];

    #pragma unroll
    for (int p = 0; p < PF; ++p) {                 // prologue: chunk 0 -> buf0
        a0[p] = pa[(size_t)p * BD];
        v0[p] = pv[(size_t)p * BD];
    }

    int t = 0;
    for (int c = 0; c < NC / 2 - 1; ++c) {         // 63 chunk pairs
        #pragma unroll
        for (int p = 0; p < PF; ++p) {             // load chunk 2c+1 -> buf1
            a1[p] = pa[(size_t)(t + PF + p) * BD];
            v1[p] = pv[(size_t)(t + PF + p) * BD];
        }
        #pragma unroll
        for (int p = 0; p < PF; ++p) SCAN_BODY(a0[p], v0[p]);   // compute chunk 2c
        #pragma unroll
        for (int p = 0; p < PF; ++p) {             // load chunk 2c+2 -> buf0
            a0[p] = pa[(size_t)(t + PF + p) * BD];
            v0[p] = pv[(size_t)(t + PF + p) * BD];
        }
        #pragma unroll
        for (int p = 0; p < PF; ++p) SCAN_BODY(a1[p], v1[p]);   // compute chunk 2c+1
    }
    // epilogue: buf0 holds chunk 126; load chunk 127, compute both
    #pragma unroll
    for (int p = 0; p < PF; ++p) {
        a1[p] = pa[(size_t)(t + PF + p) * BD];
        v1[p] = pv[(size_t)(t + PF + p) * BD];
    }
    #pragma unroll
    for (int p = 0; p < PF; ++p) SCAN_BODY(a0[p], v0[p]);
    #pragma unroll
    for (int p = 0; p < PF; ++p) SCAN_BODY(a1[p], v1[p]);
}

// ---------------------------------------------------------------------------
extern "C" void kernel_launch(void* const* d_in, const int* in_sizes, int n_in,
                              void* d_out, int out_size, void* d_ws, size_t ws_size,
                              hipStream_t stream) {
    const float* x  = (const float*)d_in[0];
    const float* h0 = (const float*)d_in[1];
    const float* Wa = (const float*)d_in[2];
    const float* ba = (const float*)d_in[3];
    const float* Wx = (const float*)d_in[4];
    const float* bv = (const float*)d_in[5];
    const float* dg = (const float*)d_in[6];
    const float* bg = (const float*)d_in[7];

    float* out_ptr = (float*)d_out;                     // [T,B,D]
    float* h_ptr   = out_ptr + (size_t)T_ * BD;         // [T+1,B,D]

    // workspace layout: xhi, xlo [32768*1024] bf16; whi, wlo [2048*1024] bf16
    u16* xhi = (u16*)d_ws;
    u16* xlo = xhi + (size_t)MM * KK;
    u16* whi = xlo + (size_t)MM * KK;
    u16* wlo = whi + (size_t)NN * KK;
    // requires ws_size >= 2*MM*KK*2 + 2*NN*KK*2 = 142.6 MB

    int n4x = MM * KK / 4;                              // 8388608
    split_kernel<<<n4x / 256, 256, 0, stream>>>(x, xhi, xlo, n4x);
    int n4w = D_ * D_ / 4;                              // 262144
    split_kernel<<<n4w / 256, 256, 0, stream>>>(Wa, whi, wlo, n4w);
    split_kernel<<<n4w / 256, 256, 0, stream>>>(Wx, whi + (size_t)D_ * KK, wlo + (size_t)D_ * KK, n4w);

    dim3 grid(NN / BN, MM / BM);                        // (16, 256)
    gemm_dual<<<grid, 256, 0, stream>>>(xhi, xlo, whi, wlo, ba, bv, out_ptr, h_ptr);

    scan_kernel<<<BD / 64, 64, 0, stream>>>(
        h_ptr + BD, out_ptr,            // alpha / v_raw sources
        out_ptr, h_ptr + BD, h_ptr,     // out / h[t+1] / h[0] destinations
        h0, dg, bg);
}

// Round 2
// 997.567 us; speedup vs baseline: 1.0600x; 1.0266x over previous
//
#include <hip/hip_runtime.h>

typedef unsigned short u16;
typedef unsigned int u32;

#define T_ 2048
#define B_ 16
#define D_ 1024
constexpr int MM = T_ * B_;     // 32768 GEMM rows
constexpr int KK = D_;          // 1024
constexpr int NN = 2 * D_;      // 2048 (alpha cols | v cols)
constexpr int BD = B_ * D_;     // 16384
constexpr int BM = 128, BN = 128, BK = 32;

typedef __bf16 bf16x8 __attribute__((ext_vector_type(8)));
typedef float f32x4 __attribute__((ext_vector_type(4)));

typedef __attribute__((address_space(3))) u32 lds_u32_t;
typedef __attribute__((address_space(1))) u32 gbl_u32_t;

__device__ __forceinline__ void gld16(void* lds, const void* g) {
    // async global->LDS, 16B per lane, dest = wave-uniform base + lane*16
    __builtin_amdgcn_global_load_lds((const gbl_u32_t*)g, (lds_u32_t*)lds, 16, 0, 0);
}

__device__ __forceinline__ float fast_exp2(float x) {
#if __has_builtin(__builtin_amdgcn_exp2f)
    return __builtin_amdgcn_exp2f(x);
#else
    return exp2f(x);
#endif
}

// ---------------- split fp32 -> bf16 hi/lo (truncation; lo corrects hi) ----
__device__ inline void split1(float f, u16& h, u16& l) {
    u32 u = __float_as_uint(f);
    h = (u16)(u >> 16);
    float fh = __uint_as_float(u & 0xffff0000u);
    float r = f - fh;                   // exact (low mantissa bits)
    l = (u16)(__float_as_uint(r) >> 16);
}

__global__ __launch_bounds__(256) void split_kernel(
    const float* __restrict__ src, u16* __restrict__ hi, u16* __restrict__ lo, int n4)
{
    int i = blockIdx.x * 256 + threadIdx.x;
    if (i >= n4) return;
    float4 v = ((const float4*)src)[i];
    u16 h0, h1, h2, h3, l0, l1, l2, l3;
    split1(v.x, h0, l0); split1(v.y, h1, l1);
    split1(v.z, h2, l2); split1(v.w, h3, l3);
    ushort4 hv; hv.x = h0; hv.y = h1; hv.z = h2; hv.w = h3;
    ushort4 lv; lv.x = l0; lv.y = l1; lv.z = l2; lv.w = l3;
    ((ushort4*)hi)[i] = hv;
    ((ushort4*)lo)[i] = lv;
}

// ---------------- fused dual GEMM: [32768,1024] x [2048,1024]^T ------------
// n<1024 -> sigmoid(.+b_alpha) = alpha  -> h region slot t+1
// n>=1024 -> tanh(.+b_v)       = v_raw  -> out region
// (unchanged this round: MfmaUtil 33% matches the 2-phase structure's cycle
// model; LDS "conflicts" are the inherent b128 8-words/bank floor, phantom.)
__global__ __launch_bounds__(256) void gemm_dual(
    const u16* __restrict__ xhi, const u16* __restrict__ xlo,
    const u16* __restrict__ whi, const u16* __restrict__ wlo,
    const float* __restrict__ ba, const float* __restrict__ bv,
    float* __restrict__ out_ptr, float* __restrict__ h_ptr)
{
    __shared__ u16 Ah[BM][BK];   // 8 KB each, rows 64B, unpadded (gld16 needs this)
    __shared__ u16 Al[BM][BK];
    __shared__ u16 Bh[BN][BK];
    __shared__ u16 Bl[BN][BK];

    const int tid  = threadIdx.x;
    const int m0   = blockIdx.y * BM;
    const int n0   = blockIdx.x * BN;
    const int wave = tid >> 6, lane = tid & 63;
    const int wm = (wave & 1) << 6;     // wave's 64-row region for MFMA
    const int wn = (wave >> 1) << 6;    // wave's 64-col region
    const int fm = lane & 15, quad = lane >> 4;
    const int wb = wave << 5;           // staging: wave covers 32 rows (2 calls x 16)
    const int rl = lane >> 2;           // staging row within 16-row group
    const int cl = (lane & 3) << 3;     // staging col (elements), 16B per lane

    f32x4 acc[4][4] = {};

    for (int k0 = 0; k0 < KK; k0 += BK) {
        size_t ga = (size_t)(m0 + wb + rl) * KK + k0 + cl;
        size_t gb = (size_t)(n0 + wb + rl) * KK + k0 + cl;
        gld16(&Ah[wb][0],      xhi + ga);
        gld16(&Ah[wb + 16][0], xhi + ga + (size_t)16 * KK);
        gld16(&Al[wb][0],      xlo + ga);
        gld16(&Al[wb + 16][0], xlo + ga + (size_t)16 * KK);
        gld16(&Bh[wb][0],      whi + gb);
        gld16(&Bh[wb + 16][0], whi + gb + (size_t)16 * KK);
        gld16(&Bl[wb][0],      wlo + gb);
        gld16(&Bl[wb + 16][0], wlo + gb + (size_t)16 * KK);
        __syncthreads();   // drains vmcnt -> LDS data visible

        bf16x8 ah[4], al[4], bh[4], bl[4];
        #pragma unroll
        for (int i = 0; i < 4; ++i) {
            ah[i] = *(const bf16x8*)&Ah[wm + i * 16 + fm][quad * 8];
            al[i] = *(const bf16x8*)&Al[wm + i * 16 + fm][quad * 8];
            bh[i] = *(const bf16x8*)&Bh[wn + i * 16 + fm][quad * 8];
            bl[i] = *(const bf16x8*)&Bl[wn + i * 16 + fm][quad * 8];
        }
        #pragma unroll
        for (int mi = 0; mi < 4; ++mi) {
            #pragma unroll
            for (int ni = 0; ni < 4; ++ni) {
                acc[mi][ni] = __builtin_amdgcn_mfma_f32_16x16x32_bf16(ah[mi], bh[ni], acc[mi][ni], 0, 0, 0);
                acc[mi][ni] = __builtin_amdgcn_mfma_f32_16x16x32_bf16(ah[mi], bl[ni], acc[mi][ni], 0, 0, 0);
                acc[mi][ni] = __builtin_amdgcn_mfma_f32_16x16x32_bf16(al[mi], bh[ni], acc[mi][ni], 0, 0, 0);
            }
        }
        __syncthreads();
    }

    const bool is_alpha = (n0 < D_);
    #pragma unroll
    for (int mi = 0; mi < 4; ++mi) {
        #pragma unroll
        for (int ni = 0; ni < 4; ++ni) {
            const int nglob = n0 + wn + ni * 16 + fm;   // C/D col = lane&15
            #pragma unroll
            for (int r = 0; r < 4; ++r) {
                const int mglob = m0 + wm + mi * 16 + quad * 4 + r;  // row=(lane>>4)*4+reg
                float z = acc[mi][ni][r];
                if (is_alpha) {
                    z += ba[nglob];
                    float s = 1.0f / (1.0f + __expf(-z));
                    h_ptr[(size_t)BD + (size_t)mglob * D_ + nglob] = s;  // alpha[t] at h slot t+1
                } else {
                    int nn = nglob - D_;
                    z += bv[nn];
                    out_ptr[(size_t)mglob * D_ + nn] = tanhf(z);         // v_raw[t] at out slot t
                }
            }
        }
    }
}

// ---------------- sequential self-gating scan ------------------------------
// MLP-starved before: register prefetch depth is compiler-controlled (each
// in-flight scalar load pins a VGPR -> compiler drains at ~8 outstanding ->
// 0.5 MB in flight chip-wide -> 1.3 TB/s). Fix: stage via global_load_lds
// (1 KB per wave-op, no VGPR held) into a 4-deep LDS ring, 3 chunks ahead,
// with HAND-COUNTED s_waitcnt vmcnt(N) (T3/T4 discipline, never 0 in the
// main loop). One wave per block -> no barriers; asm memory clobber orders
// gld16 vs ds_read. vmcnt issue-order ledger (per chunk: 4 gld16 + 16 stores):
//   steady state, after g(c): st(c-3),g(c+1),st(c-2),g(c+2),st(c-1),g(c+3)
//   = 60 ops -> wait vmcnt(56) (4 slack). Peels/tails counted below.
#define WAITV(N) asm volatile("s_waitcnt vmcnt(" #N ")" ::: "memory")

__global__ __launch_bounds__(64) void scan_kernel(
    const float* __restrict__ alpha_p,   // = h_ptr + BD   (alpha[t] at t*BD)
    const float* __restrict__ vraw_p,    // = out_ptr      (v_raw[t] at t*BD)
    float* __restrict__ out_p,           // = out_ptr      (out[t]   at t*BD)
    float* __restrict__ hout_p,          // = h_ptr + BD   (h[t+1]   at t*BD)
    float* __restrict__ h0_dst,          // = h_ptr        (h[0])
    const float* __restrict__ h0,
    const float* __restrict__ d_g, const float* __restrict__ b_g)
{
    constexpr int PF = 8;
    constexpr int NC = T_ / PF;              // 256 chunks
    __shared__ float ring[4][2][PF][64];     // 16 KB: [buf][stream][t][col]

    const int lane = threadIdx.x;            // 0..63, one wave per block
    const int c0   = blockIdx.x * 64;        // this block's 64 columns
    const int i    = c0 + lane;
    const int d    = i & (D_ - 1);
    constexpr float L2E = 1.44269504088896f;
    const float ndg = -d_g[d] * L2E;
    const float nbg = -b_g[d] * L2E;
    float h = h0[i];
    h0_dst[i] = h;                           // h[0]

    const float* po = out_p + i;             // stores keep lane->col mapping
    const float* dummy = po; (void)dummy;
    float* pov = out_p + i;
    float* phv = hout_p + i;

    // gld16 source: call j (j=0,1) of chunk c covers t = c*PF + 4j + (lane>>4),
    // cols c0 + (lane&15)*4 .. +3  (16 B / lane). LDS lands row-major [t][col].
    const size_t gcol = (size_t)c0 + (size_t)((lane & 15) << 2);
    const int trow = lane >> 4;              // 0..3

#define ISSUE(c_) do {                                                        \
    const int b_ = (c_) & 3;                                                  \
    const size_t t0_ = (size_t)((c_) * PF + trow) * BD + gcol;                \
    gld16(&ring[b_][0][0][0], alpha_p + t0_);                                 \
    gld16(&ring[b_][0][4][0], alpha_p + t0_ + (size_t)4 * BD);                \
    gld16(&ring[b_][1][0][0], vraw_p  + t0_);                                 \
    gld16(&ring[b_][1][4][0], vraw_p  + t0_ + (size_t)4 * BD);                \
} while (0)

#define COMPUTE(c_) do {                                                      \
    const int b_ = (c_) & 3;                                                  \
    _Pragma("unroll")                                                         \
    for (int p = 0; p < PF; ++p) {                                            \
        float a_  = ring[b_][0][p][lane];                                     \
        float vr_ = ring[b_][1][p][lane];                                     \
        float e_  = fast_exp2(__builtin_fmaf(ndg, h, nbg));                   \
        float g_  = __builtin_amdgcn_rcpf(1.0f + e_);                         \
        float v_  = vr_ * g_;                                                 \
        h = __builtin_fmaf(a_, h - v_, v_);                                   \
        float sg_ = __builtin_amdgcn_rcpf(1.0f + fast_exp2(h * -L2E));        \
        const size_t off_ = (size_t)((c_) * PF + p) * BD;                     \
        __builtin_nontemporal_store(h * h * sg_, pov + off_);                 \
        __builtin_nontemporal_store(h, phv + off_);                           \
    }                                                                         \
} while (0)

    ISSUE(0); ISSUE(1); ISSUE(2);            // prologue: 12 gld16 in flight

    // peels (exact counts minus 4 slack):
    ISSUE(3); WAITV(8);  COMPUTE(0);         // after g0: g1,g2,g3 = 12
    ISSUE(4); WAITV(24); COMPUTE(1);         // after g1: g2,g3,st0,g4 = 28
    ISSUE(5); WAITV(40); COMPUTE(2);         // after g2: g3,st0,g4,st1,g5 = 44

    for (int c = 3; c < NC - 3; ++c) {       // steady: after g(c) = 60 ops
        ISSUE(c + 3);
        WAITV(56);
        COMPUTE(c);
    }

    WAITV(52); COMPUTE(NC - 3);              // exact 56
    WAITV(48); COMPUTE(NC - 2);              // exact 52
    WAITV(44); COMPUTE(NC - 1);              // exact 48

#undef ISSUE
#undef COMPUTE
}

// ---------------------------------------------------------------------------
extern "C" void kernel_launch(void* const* d_in, const int* in_sizes, int n_in,
                              void* d_out, int out_size, void* d_ws, size_t ws_size,
                              hipStream_t stream) {
    const float* x  = (const float*)d_in[0];
    const float* h0 = (const float*)d_in[1];
    const float* Wa = (const float*)d_in[2];
    const float* ba = (const float*)d_in[3];
    const float* Wx = (const float*)d_in[4];
    const float* bv = (const float*)d_in[5];
    const float* dg = (const float*)d_in[6];
    const float* bg = (const float*)d_in[7];

    float* out_ptr = (float*)d_out;                     // [T,B,D]
    float* h_ptr   = out_ptr + (size_t)T_ * BD;         // [T+1,B,D]

    // workspace layout: xhi, xlo [32768*1024] bf16; whi, wlo [2048*1024] bf16
    u16* xhi = (u16*)d_ws;
    u16* xlo = xhi + (size_t)MM * KK;
    u16* whi = xlo + (size_t)MM * KK;
    u16* wlo = whi + (size_t)NN * KK;
    // requires ws_size >= 2*MM*KK*2 + 2*NN*KK*2 = 142.6 MB

    int n4x = MM * KK / 4;                              // 8388608
    split_kernel<<<n4x / 256, 256, 0, stream>>>(x, xhi, xlo, n4x);
    int n4w = D_ * D_ / 4;                              // 262144
    split_kernel<<<n4w / 256, 256, 0, stream>>>(Wa, whi, wlo, n4w);
    split_kernel<<<n4w / 256, 256, 0, stream>>>(Wx, whi + (size_t)D_ * KK, wlo + (size_t)D_ * KK, n4w);

    dim3 grid(NN / BN, MM / BM);                        // (16, 256)
    gemm_dual<<<grid, 256, 0, stream>>>(xhi, xlo, whi, wlo, ba, bv, out_ptr, h_ptr);

    scan_kernel<<<BD / 64, 64, 0, stream>>>(
        h_ptr + BD, out_ptr,            // alpha / v_raw sources
        out_ptr, h_ptr + BD, h_ptr,     // out / h[t+1] / h[0] destinations
        h0, dg, bg);
}

// Round 3
// 945.478 us; speedup vs baseline: 1.1183x; 1.0551x over previous
//
#include <hip/hip_runtime.h>

typedef unsigned short u16;
typedef unsigned int u32;

#define T_ 2048
#define B_ 16
#define D_ 1024
constexpr int MM = T_ * B_;     // 32768 GEMM rows
constexpr int KK = D_;          // 1024
constexpr int NN = 2 * D_;      // 2048 (alpha cols | v cols)
constexpr int BD = B_ * D_;     // 16384
constexpr int BM = 256, BN = 256, BK = 32;
constexpr int NT = KK / BK;     // 32 K-steps

typedef __bf16 bf16x8 __attribute__((ext_vector_type(8)));
typedef float f32x4 __attribute__((ext_vector_type(4)));

typedef __attribute__((address_space(3))) u32 lds_u32_t;
typedef __attribute__((address_space(1))) u32 gbl_u32_t;

__device__ __forceinline__ void gld16(void* lds, const void* g) {
    // async global->LDS, 16B per lane, dest = wave-uniform base + lane*16
    __builtin_amdgcn_global_load_lds((const gbl_u32_t*)g, (lds_u32_t*)lds, 16, 0, 0);
}

__device__ __forceinline__ float fast_exp2(float x) {
#if __has_builtin(__builtin_amdgcn_exp2f)
    return __builtin_amdgcn_exp2f(x);
#else
    return exp2f(x);
#endif
}

// ---------------- split fp32 -> bf16 hi/lo (truncation; lo corrects hi) ----
__device__ inline void split1(float f, u16& h, u16& l) {
    u32 u = __float_as_uint(f);
    h = (u16)(u >> 16);
    float fh = __uint_as_float(u & 0xffff0000u);
    float r = f - fh;                   // exact (low mantissa bits)
    l = (u16)(__float_as_uint(r) >> 16);
}

__global__ __launch_bounds__(256) void split_kernel(
    const float* __restrict__ src, u16* __restrict__ hi, u16* __restrict__ lo, int n4)
{
    int i = blockIdx.x * 256 + threadIdx.x;
    if (i >= n4) return;
    float4 v = ((const float4*)src)[i];
    u16 h0, h1, h2, h3, l0, l1, l2, l3;
    split1(v.x, h0, l0); split1(v.y, h1, l1);
    split1(v.z, h2, l2); split1(v.w, h3, l3);
    ushort4 hv; hv.x = h0; hv.y = h1; hv.z = h2; hv.w = h3;
    ushort4 lv; lv.x = l0; lv.y = l1; lv.z = l2; lv.w = l3;
    ((ushort4*)hi)[i] = hv;
    ((ushort4*)lo)[i] = lv;
}

// ---------------- fused dual GEMM: [32768,1024] x [2048,1024]^T ------------
// 256x256 tile, BK=32, 8 waves (2M x 4N), double-buffered 128KB LDS.
// Schedule: prefetch K-step t+1's gld16s BEFORE computing t; single
// __syncthreads per K-step. Its implicit vmcnt(0) drain is free: per-CU
// MFMA work per K-step = 768 mfma x ~4.85cy = ~3700cy >> load latency,
// so the prefetch lands long before the barrier. This escapes the m97
// 2-barrier-128^2 ceiling (load latency fully exposed each K-step).
// n<1024 -> sigmoid(.+b_alpha) = alpha  -> h region slot t+1
// n>=1024 -> tanh(.+b_v)       = v_raw  -> out region
__global__ __launch_bounds__(512, 2) void gemm_dual(
    const u16* __restrict__ xhi, const u16* __restrict__ xlo,
    const u16* __restrict__ whi, const u16* __restrict__ wlo,
    const float* __restrict__ ba, const float* __restrict__ bv,
    float* __restrict__ out_ptr, float* __restrict__ h_ptr)
{
    __shared__ u16 Ah[2][BM][BK];   // 16KB each buf half; rows 64B, unpadded
    __shared__ u16 Al[2][BM][BK];
    __shared__ u16 Bh[2][BN][BK];
    __shared__ u16 Bl[2][BN][BK];   // total 128 KB

    const int tid  = threadIdx.x;
    const int m0   = blockIdx.y * BM;
    const int n0   = blockIdx.x * BN;
    const int wave = tid >> 6, lane = tid & 63;
    const int wm = (wave >> 2) << 7;    // 0 / 128 : wave's 128-row region
    const int wn = (wave & 3) << 6;     // 0/64/128/192 : wave's 64-col region
    const int fm = lane & 15, quad = lane >> 4;
    const int wb = wave << 5;           // staging: wave covers 32 rows of each tile
    const int rl = lane >> 2;           // staging row within 16-row group
    const int cl = (lane & 3) << 3;     // staging col (elements), 16B per lane

    f32x4 acc[8][4] = {};

    const size_t rowA = (size_t)(m0 + wb + rl) * KK + cl;   // k0 added per step
    const size_t rowB = (size_t)(n0 + wb + rl) * KK + cl;

#define STAGE(buf_, k_) do {                                                  \
    size_t ga = rowA + (size_t)(k_);                                          \
    size_t gb = rowB + (size_t)(k_);                                          \
    gld16(&Ah[buf_][wb][0],      xhi + ga);                                   \
    gld16(&Ah[buf_][wb + 16][0], xhi + ga + (size_t)16 * KK);                 \
    gld16(&Al[buf_][wb][0],      xlo + ga);                                   \
    gld16(&Al[buf_][wb + 16][0], xlo + ga + (size_t)16 * KK);                 \
    gld16(&Bh[buf_][wb][0],      whi + gb);                                   \
    gld16(&Bh[buf_][wb + 16][0], whi + gb + (size_t)16 * KK);                 \
    gld16(&Bl[buf_][wb][0],      wlo + gb);                                   \
    gld16(&Bl[buf_][wb + 16][0], wlo + gb + (size_t)16 * KK);                 \
} while (0)

    STAGE(0, 0);                 // prologue: K-step 0 -> buf 0
    __syncthreads();             // drains vmcnt -> buf 0 visible to all waves

    for (int t = 0; t < NT; ++t) {
        const int cur = t & 1;
        if (t + 1 < NT) {
            const int nxt = cur ^ 1;
            STAGE(nxt, (t + 1) * BK);   // prefetch: flies under this step's MFMA
        }

        bf16x8 bh[4], bl[4];
        #pragma unroll
        for (int ni = 0; ni < 4; ++ni) {
            bh[ni] = *(const bf16x8*)&Bh[cur][wn + ni * 16 + fm][quad * 8];
            bl[ni] = *(const bf16x8*)&Bl[cur][wn + ni * 16 + fm][quad * 8];
        }
        #pragma unroll
        for (int mi = 0; mi < 8; ++mi) {
            bf16x8 ah = *(const bf16x8*)&Ah[cur][wm + mi * 16 + fm][quad * 8];
            bf16x8 al = *(const bf16x8*)&Al[cur][wm + mi * 16 + fm][quad * 8];
            #pragma unroll
            for (int ni = 0; ni < 4; ++ni) {
                acc[mi][ni] = __builtin_amdgcn_mfma_f32_16x16x32_bf16(ah, bh[ni], acc[mi][ni], 0, 0, 0);
                acc[mi][ni] = __builtin_amdgcn_mfma_f32_16x16x32_bf16(ah, bl[ni], acc[mi][ni], 0, 0, 0);
                acc[mi][ni] = __builtin_amdgcn_mfma_f32_16x16x32_bf16(al, bh[ni], acc[mi][ni], 0, 0, 0);
            }
        }
        __syncthreads();   // all waves done reading buf[cur]; nxt data landed
    }
#undef STAGE

    const bool is_alpha = (n0 < D_);
    #pragma unroll
    for (int mi = 0; mi < 8; ++mi) {
        #pragma unroll
        for (int ni = 0; ni < 4; ++ni) {
            const int nglob = n0 + wn + ni * 16 + fm;   // C/D col = lane&15
            #pragma unroll
            for (int r = 0; r < 4; ++r) {
                const int mglob = m0 + wm + mi * 16 + quad * 4 + r;  // row=(lane>>4)*4+reg
                float z = acc[mi][ni][r];
                if (is_alpha) {
                    z += ba[nglob];
                    float s = 1.0f / (1.0f + __expf(-z));
                    h_ptr[(size_t)BD + (size_t)mglob * D_ + nglob] = s;  // alpha[t] at h slot t+1
                } else {
                    int nn = nglob - D_;
                    z += bv[nn];
                    out_ptr[(size_t)mglob * D_ + nn] = tanhf(z);         // v_raw[t] at out slot t
                }
            }
        }
    }
}

// ---------------- sequential self-gating scan (unchanged from R2) ----------
#define WAITV(N) asm volatile("s_waitcnt vmcnt(" #N ")" ::: "memory")

__global__ __launch_bounds__(64) void scan_kernel(
    const float* __restrict__ alpha_p,   // = h_ptr + BD   (alpha[t] at t*BD)
    const float* __restrict__ vraw_p,    // = out_ptr      (v_raw[t] at t*BD)
    float* __restrict__ out_p,           // = out_ptr      (out[t]   at t*BD)
    float* __restrict__ hout_p,          // = h_ptr + BD   (h[t+1]   at t*BD)
    float* __restrict__ h0_dst,          // = h_ptr        (h[0])
    const float* __restrict__ h0,
    const float* __restrict__ d_g, const float* __restrict__ b_g)
{
    constexpr int PF = 8;
    constexpr int NC = T_ / PF;              // 256 chunks
    __shared__ float ring[4][2][PF][64];     // 16 KB: [buf][stream][t][col]

    const int lane = threadIdx.x;            // 0..63, one wave per block
    const int c0   = blockIdx.x * 64;        // this block's 64 columns
    const int i    = c0 + lane;
    const int d    = i & (D_ - 1);
    constexpr float L2E = 1.44269504088896f;
    const float ndg = -d_g[d] * L2E;
    const float nbg = -b_g[d] * L2E;
    float h = h0[i];
    h0_dst[i] = h;                           // h[0]

    float* pov = out_p + i;
    float* phv = hout_p + i;

    const size_t gcol = (size_t)c0 + (size_t)((lane & 15) << 2);
    const int trow = lane >> 4;              // 0..3

#define ISSUE(c_) do {                                                        \
    const int b_ = (c_) & 3;                                                  \
    const size_t t0_ = (size_t)((c_) * PF + trow) * BD + gcol;                \
    gld16(&ring[b_][0][0][0], alpha_p + t0_);                                 \
    gld16(&ring[b_][0][4][0], alpha_p + t0_ + (size_t)4 * BD);                \
    gld16(&ring[b_][1][0][0], vraw_p  + t0_);                                 \
    gld16(&ring[b_][1][4][0], vraw_p  + t0_ + (size_t)4 * BD);                \
} while (0)

#define COMPUTE(c_) do {                                                      \
    const int b_ = (c_) & 3;                                                  \
    _Pragma("unroll")                                                         \
    for (int p = 0; p < PF; ++p) {                                            \
        float a_  = ring[b_][0][p][lane];                                     \
        float vr_ = ring[b_][1][p][lane];                                     \
        float e_  = fast_exp2(__builtin_fmaf(ndg, h, nbg));                   \
        float g_  = __builtin_amdgcn_rcpf(1.0f + e_);                         \
        float v_  = vr_ * g_;                                                 \
        h = __builtin_fmaf(a_, h - v_, v_);                                   \
        float sg_ = __builtin_amdgcn_rcpf(1.0f + fast_exp2(h * -L2E));        \
        const size_t off_ = (size_t)((c_) * PF + p) * BD;                     \
        __builtin_nontemporal_store(h * h * sg_, pov + off_);                 \
        __builtin_nontemporal_store(h, phv + off_);                           \
    }                                                                         \
} while (0)

    ISSUE(0); ISSUE(1); ISSUE(2);            // prologue: 12 gld16 in flight

    ISSUE(3); WAITV(8);  COMPUTE(0);
    ISSUE(4); WAITV(24); COMPUTE(1);
    ISSUE(5); WAITV(40); COMPUTE(2);

    for (int c = 3; c < NC - 3; ++c) {
        ISSUE(c + 3);
        WAITV(56);
        COMPUTE(c);
    }

    WAITV(52); COMPUTE(NC - 3);
    WAITV(48); COMPUTE(NC - 2);
    WAITV(44); COMPUTE(NC - 1);

#undef ISSUE
#undef COMPUTE
}

// ---------------------------------------------------------------------------
extern "C" void kernel_launch(void* const* d_in, const int* in_sizes, int n_in,
                              void* d_out, int out_size, void* d_ws, size_t ws_size,
                              hipStream_t stream) {
    const float* x  = (const float*)d_in[0];
    const float* h0 = (const float*)d_in[1];
    const float* Wa = (const float*)d_in[2];
    const float* ba = (const float*)d_in[3];
    const float* Wx = (const float*)d_in[4];
    const float* bv = (const float*)d_in[5];
    const float* dg = (const float*)d_in[6];
    const float* bg = (const float*)d_in[7];

    float* out_ptr = (float*)d_out;                     // [T,B,D]
    float* h_ptr   = out_ptr + (size_t)T_ * BD;         // [T+1,B,D]

    // workspace layout: xhi, xlo [32768*1024] bf16; whi, wlo [2048*1024] bf16
    u16* xhi = (u16*)d_ws;
    u16* xlo = xhi + (size_t)MM * KK;
    u16* whi = xlo + (size_t)MM * KK;
    u16* wlo = whi + (size_t)NN * KK;
    // requires ws_size >= 2*MM*KK*2 + 2*NN*KK*2 = 142.6 MB

    int n4x = MM * KK / 4;                              // 8388608
    split_kernel<<<n4x / 256, 256, 0, stream>>>(x, xhi, xlo, n4x);
    int n4w = D_ * D_ / 4;                              // 262144
    split_kernel<<<n4w / 256, 256, 0, stream>>>(Wa, whi, wlo, n4w);
    split_kernel<<<n4w / 256, 256, 0, stream>>>(Wx, whi + (size_t)D_ * KK, wlo + (size_t)D_ * KK, n4w);

    dim3 grid(NN / BN, MM / BM);                        // (8, 128) = 1024 blocks
    gemm_dual<<<grid, 512, 0, stream>>>(xhi, xlo, whi, wlo, ba, bv, out_ptr, h_ptr);

    scan_kernel<<<BD / 64, 64, 0, stream>>>(
        h_ptr + BD, out_ptr,            // alpha / v_raw sources
        out_ptr, h_ptr + BD, h_ptr,     // out / h[t+1] / h[0] destinations
        h0, dg, bg);
}